// Round 8
// baseline (144.294 us; speedup 1.0000x reference)
//
#include <hip/hip_runtime.h>
#include <hip/hip_bf16.h>

// MDTA: LN -> 1x1 conv (QKV) -> dw3x3 -> spatial attention (N=4096, d=24, 8 heads) -> proj + residual
// This round: LayerNorm fused into the QKV GEMM (B-fragments built on the fly from fp32 x with
// precomputed per-pixel mean/rstd) — xln buffer and LN dispatch eliminated.

typedef __bf16 bf16;
typedef __bf16 bf16x2 __attribute__((ext_vector_type(2)));
typedef __bf16 bf16x4 __attribute__((ext_vector_type(4)));
typedef __bf16 bf16x8 __attribute__((ext_vector_type(8)));
typedef float f32x4 __attribute__((ext_vector_type(4)));

#define C_DIM 192
#define N_PIX 4096
#define HEADS 8
#define DHEAD 24
#define DPAD 32
#define C3 576
#define NSPLIT 8

__device__ inline float fast_exp2(float x) {
#if __has_builtin(__builtin_amdgcn_exp2f)
    return __builtin_amdgcn_exp2f(x);
#else
    return exp2f(x);
#endif
}

__device__ inline f32x4 mfma16(bf16x8 a, bf16x8 b, f32x4 c) {
    return __builtin_amdgcn_mfma_f32_16x16x32_bf16(a, b, c, 0, 0, 0);
}

// ---------------- prep: LN stats (blocks 0..15) + weight cvt (blocks 16..447) ----------------
__global__ __launch_bounds__(256) void prep(const float* __restrict__ x,
                                            float* __restrict__ mu,
                                            float* __restrict__ rs,
                                            const float* __restrict__ wqkv,
                                            const float* __restrict__ wproj,
                                            bf16* __restrict__ wqkv_b,
                                            bf16* __restrict__ wproj_b,
                                            float* __restrict__ maxk2) {
    int b = blockIdx.x, t = threadIdx.x;
    if (b >= 16) {
        int idx = (b - 16) * 256 + t;
        if (idx < C3 * C_DIM) wqkv_b[idx] = (bf16)wqkv[idx];
        if (idx < C_DIM * C_DIM) wproj_b[idx] = (bf16)wproj[idx];
        if (b == 16 && t < 8) maxk2[t] = 0.0f;
        return;
    }
    int n = b * 256 + t;                    // fully coalesced column sums
    float s = 0.f, ss = 0.f;
    for (int c = 0; c < C_DIM; ++c) {
        float f = x[(size_t)c * N_PIX + n];
        s += f; ss += f * f;
    }
    float mean = s * (1.0f / C_DIM);
    float var = ss * (1.0f / C_DIM) - mean * mean;
    mu[n] = mean;
    rs[n] = rsqrtf(var + 1e-5f);
}

// ---------------- QKV GEMM with fused LN: out[M,4096] = W[M,192] * LN(x)[192,4096] ----------------
// B-fragment built on the fly: b[k][n] = (x[k][n]-mu[n])*rs[n]*gamma[k]+beta[k], fp32 math.
__global__ __launch_bounds__(256) void gemm192_ln(const bf16* __restrict__ A,
                                                  const float* __restrict__ x,
                                                  const float* __restrict__ mu,
                                                  const float* __restrict__ rs,
                                                  const float* __restrict__ gamma,
                                                  const float* __restrict__ beta,
                                                  bf16* __restrict__ outb) {
    const int K = 192;
    int n0 = blockIdx.x * 64;
    int m0 = blockIdx.y * 64;
    int tid = threadIdx.x;
    int wave = tid >> 6, lane = tid & 63;
    int l16 = lane & 15, quad = lane >> 4;
    int wm = (wave >> 1) * 32, wn = (wave & 1) * 32;
    int nb0 = n0 + wn + l16, nb1 = nb0 + 16;
    float a0n = rs[nb0], c0n = -mu[nb0] * a0n;
    float a1n = rs[nb1], c1n = -mu[nb1] * a1n;
    f32x4 acc[2][2] = {};
    for (int kk = 0; kk < K; kk += 32) {
        int k0 = kk + quad * 8;
        float4 g0 = *(const float4*)(gamma + k0);
        float4 g1 = *(const float4*)(gamma + k0 + 4);
        float4 e0 = *(const float4*)(beta + k0);
        float4 e1 = *(const float4*)(beta + k0 + 4);
        float gk[8] = {g0.x, g0.y, g0.z, g0.w, g1.x, g1.y, g1.z, g1.w};
        float ek[8] = {e0.x, e0.y, e0.z, e0.w, e1.x, e1.y, e1.z, e1.w};
        bf16x8 b0f, b1f;
        for (int j = 0; j < 8; ++j) {
            float xv0 = x[(size_t)(k0 + j) * N_PIX + nb0];
            float xv1 = x[(size_t)(k0 + j) * N_PIX + nb1];
            float t0 = __builtin_fmaf(xv0, a0n, c0n);
            float t1 = __builtin_fmaf(xv1, a1n, c1n);
            b0f[j] = (bf16)__builtin_fmaf(t0, gk[j], ek[j]);
            b1f[j] = (bf16)__builtin_fmaf(t1, gk[j], ek[j]);
        }
        bf16x8 a0 = *(const bf16x8*)(A + (m0 + wm + l16) * K + k0);
        bf16x8 a1 = *(const bf16x8*)(A + (m0 + wm + 16 + l16) * K + k0);
        acc[0][0] = mfma16(a0, b0f, acc[0][0]);
        acc[0][1] = mfma16(a0, b1f, acc[0][1]);
        acc[1][0] = mfma16(a1, b0f, acc[1][0]);
        acc[1][1] = mfma16(a1, b1f, acc[1][1]);
    }
    for (int i = 0; i < 2; ++i)
        for (int j = 0; j < 2; ++j)
            for (int r = 0; r < 4; ++r) {
                int row = m0 + wm + i * 16 + quad * 4 + r;
                int col = n0 + wn + j * 16 + l16;
                outb[(size_t)row * N_PIX + col] = (bf16)acc[i][j][r];
            }
}

// ---------------- proj GEMM (64m x 32n tile) + fp32 residual epilogue (prefetched) ----------------
__global__ __launch_bounds__(256) void gemm_proj(const bf16* __restrict__ A,
                                                 const bf16* __restrict__ BT,
                                                 float* __restrict__ outf,
                                                 const float* __restrict__ resid) {
    const int K = 192;
    int n0 = blockIdx.x * 32;
    int m0 = blockIdx.y * 64;
    int tid = threadIdx.x;
    int wave = tid >> 6, lane = tid & 63;
    int l16 = lane & 15, quad = lane >> 4;
    int mrow = m0 + wave * 16;
    float rv[8];
    for (int j = 0; j < 2; ++j)
        for (int r = 0; r < 4; ++r)
            rv[j * 4 + r] = resid[(size_t)(mrow + quad * 4 + r) * N_PIX + n0 + j * 16 + l16];
    f32x4 acc[2] = {};
    for (int kk = 0; kk < K; kk += 32) {
        bf16x8 a = *(const bf16x8*)(A + (mrow + l16) * K + kk + quad * 8);
        bf16x8 b0 = *(const bf16x8*)(BT + (n0 + l16) * K + kk + quad * 8);
        bf16x8 b1 = *(const bf16x8*)(BT + (n0 + 16 + l16) * K + kk + quad * 8);
        acc[0] = mfma16(a, b0, acc[0]);
        acc[1] = mfma16(a, b1, acc[1]);
    }
    for (int j = 0; j < 2; ++j)
        for (int r = 0; r < 4; ++r) {
            int row = mrow + quad * 4 + r;
            int col = n0 + j * 16 + l16;
            outf[(size_t)row * N_PIX + col] = acc[j][r] + rv[j * 4 + r];
        }
}

// ---------------- depthwise 3x3 + bias, vectorized ----------------
__global__ __launch_bounds__(256) void dwconv(const bf16* __restrict__ qkv,
                                              const float* __restrict__ wdw,
                                              const float* __restrict__ bdw,
                                              bf16* __restrict__ qt,
                                              bf16* __restrict__ kt,
                                              bf16* __restrict__ vl,
                                              float* __restrict__ maxk2) {
    __shared__ float k2s[24][64];
    int bx = blockIdx.x;
    int part = bx >> 9;            // 512 blocks per part
    int h = (bx >> 6) & 7;
    int y = bx & 63;
    int t = threadIdx.x;
    int ch_local = t >> 3;         // 0..31 (24 active)
    int seg = t & 7;
    int px0 = seg * 8;
    bool active = ch_local < 24;

    float acc[8];
    if (active) {
        int ch = part * C_DIM + h * DHEAD + ch_local;
        const bf16* in = qkv + (size_t)ch * N_PIX;
        float w[9];
        for (int i = 0; i < 9; ++i) w[i] = wdw[ch * 9 + i];
        float bias = bdw[ch];
        float rowv[3][10];
        for (int r = 0; r < 3; ++r) {
            int yy = y + r - 1;
            if (yy >= 0 && yy < 64) {
                bf16x8 v8 = *(const bf16x8*)(in + yy * 64 + px0);
                for (int j = 0; j < 8; ++j) rowv[r][j + 1] = (float)v8[j];
                rowv[r][0] = (seg > 0) ? (float)in[yy * 64 + px0 - 1] : 0.f;
                rowv[r][9] = (seg < 7) ? (float)in[yy * 64 + px0 + 8] : 0.f;
            } else {
                for (int j = 0; j < 10; ++j) rowv[r][j] = 0.f;
            }
        }
        for (int j = 0; j < 8; ++j) {
            float a = bias;
            for (int r = 0; r < 3; ++r)
                a += w[r * 3 + 0] * rowv[r][j] + w[r * 3 + 1] * rowv[r][j + 1]
                   + w[r * 3 + 2] * rowv[r][j + 2];
            acc[j] = a;
        }
    }

    if (part == 2) {
        if (active) {
            bf16x8 v8;
            for (int j = 0; j < 8; ++j) v8[j] = (bf16)acc[j];
            *(bf16x8*)(vl + ((size_t)(h * DPAD + ch_local)) * N_PIX + y * 64 + px0) = v8;
        } else {
            int i = t - 192;           // pad rows 24..31 x 8 segments
            int dd = 24 + (i >> 3);
            int s2 = i & 7;
            bf16 val = (bf16)((dd == 24) ? 1.0f : 0.0f);
            bf16x8 v8;
            for (int j = 0; j < 8; ++j) v8[j] = val;
            *(bf16x8*)(vl + ((size_t)(h * DPAD + dd)) * N_PIX + y * 64 + s2 * 8) = v8;
        }
    } else {
        bf16* dst = (part == 0 ? qt : kt) + ((size_t)h * N_PIX + y * 64) * DPAD;
        if (active) {
            for (int j = 0; j < 8; ++j)
                dst[(size_t)(px0 + j) * DPAD + ch_local] = (bf16)acc[j];
        } else {
            int i = t - 192;           // one px each, zero dd 24..31
            bf16x8 z;
            for (int j = 0; j < 8; ++j) z[j] = (bf16)0.0f;
            *(bf16x8*)(dst + (size_t)i * DPAD + 24) = z;
        }
        if (part == 1) {
            if (active)
                for (int j = 0; j < 8; ++j) k2s[ch_local][px0 + j] = acc[j] * acc[j];
            __syncthreads();
            if (t < 64) {
                float s = 0.f;
                for (int c = 0; c < 24; ++c) s += k2s[c][t];
                for (int off = 1; off < 64; off <<= 1)
                    s = fmaxf(s, __shfl_xor(s, off, 64));
                if (t == 0) atomicMax((unsigned int*)(maxk2 + h), __float_as_uint(s));
            }
        }
    }
}

// ---------------- flash attention: fat waves (64 q/wave), no barriers, split-K=8 ----------------
__global__ __launch_bounds__(256, 4) void flash_attn(const bf16* __restrict__ qt,
                                                     const bf16* __restrict__ kt,
                                                     const bf16* __restrict__ vl,
                                                     const float* __restrict__ temp,
                                                     const float* __restrict__ maxk2,
                                                     bf16* __restrict__ opart,
                                                     bf16* __restrict__ lpart) {
    __shared__ __align__(16) bf16 Plds[4 * 4096];   // 8KB per wave: [f(4)][chunk(8)][l16(16)][8]

    int tid = threadIdx.x;
    int wave = tid >> 6, lane = tid & 63;
    int l16 = lane & 15, quad = lane >> 4;
    int head = blockIdx.x & 7;               // block -> XCD round-robin: head pinned per XCD
    int qb = (blockIdx.x >> 3) & 15;
    int split = blockIdx.x >> 7;             // 0..7
    int nbase = qb * 256 + wave * 64;
    float tl = temp[head] * 1.44269504f;

    const bf16* qrow = qt + ((size_t)head * N_PIX + nbase) * DPAD;
    bf16x8 aq[4];
    for (int f = 0; f < 4; ++f)
        aq[f] = *(const bf16x8*)(qrow + (size_t)(f * 16 + l16) * DPAD + quad * 8);

    float mk2 = maxk2[head];
    float Bb[4];
    for (int f = 0; f < 4; ++f) {
        float q2 = 0.f;
        for (int j = 0; j < 8; ++j) { float v = (float)aq[f][j]; q2 += v * v; }
        q2 += __shfl_xor(q2, 16, 64);
        q2 += __shfl_xor(q2, 32, 64);
        Bb[f] = fabsf(tl) * sqrtf(q2 * mk2) + 1.0f;
    }

    const bf16* kbase = kt + (size_t)head * N_PIX * DPAD;
    const bf16* vbase = vl + (size_t)head * DPAD * N_PIX;
    bf16* pw = Plds + wave * 4096;

    f32x4 o0[4] = {}, o1[4] = {};

    #pragma unroll 2
    for (int it = 0; it < 64 / NSPLIT; ++it) {
        int m0 = (split * (64 / NSPLIT) + it) * 64;
        bf16x8 ak[4];
        for (int mt = 0; mt < 4; ++mt)
            ak[mt] = *(const bf16x8*)(kbase + (size_t)(m0 + mt * 16 + l16) * DPAD + quad * 8);
        bf16x8 av[4];
        av[0] = *(const bf16x8*)(vbase + (size_t)l16 * N_PIX + m0 + quad * 8);
        av[1] = *(const bf16x8*)(vbase + (size_t)(16 + l16) * N_PIX + m0 + quad * 8);
        av[2] = *(const bf16x8*)(vbase + (size_t)l16 * N_PIX + m0 + 32 + quad * 8);
        av[3] = *(const bf16x8*)(vbase + (size_t)(16 + l16) * N_PIX + m0 + 32 + quad * 8);

        for (int f = 0; f < 4; ++f) {
            f32x4 z = {0.f, 0.f, 0.f, 0.f};
            f32x4 st[4];
            for (int mt = 0; mt < 4; ++mt) st[mt] = mfma16(ak[mt], aq[f], z);
            for (int mt = 0; mt < 4; ++mt) {
                bf16x4 pk;
                for (int r = 0; r < 4; ++r)
                    pk[r] = (bf16)fast_exp2(__builtin_fmaf(st[mt][r], tl, -Bb[f]));
                int chunk = mt * 2 + (quad >> 1);
                *(bf16x4*)(pw + f * 1024 + (chunk * 16 + l16) * 8 + (quad & 1) * 4) = pk;
            }
        }
        for (int f = 0; f < 4; ++f) {
            bf16x8 ap0 = *(const bf16x8*)(pw + f * 1024 + (quad * 16 + l16) * 8);
            bf16x8 ap1 = *(const bf16x8*)(pw + f * 1024 + ((4 + quad) * 16 + l16) * 8);
            o0[f] = mfma16(av[0], ap0, o0[f]);
            o1[f] = mfma16(av[1], ap0, o1[f]);
            o0[f] = mfma16(av[2], ap1, o0[f]);
            o1[f] = mfma16(av[3], ap1, o1[f]);
        }
    }

    for (int f = 0; f < 4; ++f) {
        int n = nbase + f * 16 + l16;
        size_t rowo = ((size_t)(split * 8 + head) * N_PIX + n) * 24;
        bf16x4 w0;
        for (int r = 0; r < 4; ++r) w0[r] = (bf16)o0[f][r];
        *(bf16x4*)(opart + rowo + quad * 4) = w0;
        if (quad < 2) {
            bf16x4 w1;
            for (int r = 0; r < 4; ++r) w1[r] = (bf16)o1[f][r];
            *(bf16x4*)(opart + rowo + 16 + quad * 4) = w1;
        }
        if (quad == 2)
            lpart[(size_t)(split * 8 + head) * N_PIX + n] = (bf16)o1[f][0];
    }
}

// ---------------- combine split-K partials -> outt[n][c] bf16 (coalesced rows) ----------------
__global__ __launch_bounds__(256) void combine(const bf16* __restrict__ opart,
                                               const bf16* __restrict__ lpart,
                                               bf16* __restrict__ outt) {
    int idx = blockIdx.x * 256 + threadIdx.x;   // 8*4096 threads, one (h,n) row each
    int n = idx & 4095;
    int h = idx >> 12;
    float acc[24];
    for (int j = 0; j < 24; ++j) acc[j] = 0.f;
    float l = 0.f;
    for (int s = 0; s < NSPLIT; ++s) {
        const bf16* row = opart + ((size_t)(s * 8 + h) * N_PIX + n) * 24;
        bf16x8 a = *(const bf16x8*)(row);
        bf16x8 b = *(const bf16x8*)(row + 8);
        bf16x8 c = *(const bf16x8*)(row + 16);
        for (int j = 0; j < 8; ++j) {
            acc[j] += (float)a[j];
            acc[8 + j] += (float)b[j];
            acc[16 + j] += (float)c[j];
        }
        l += (float)lpart[(size_t)(s * 8 + h) * N_PIX + n];
    }
    float inv = 1.0f / l;
    bf16* dst = outt + (size_t)n * C_DIM + h * DHEAD;
    for (int g = 0; g < 3; ++g) {
        bf16x8 w;
        for (int j = 0; j < 8; ++j) w[j] = (bf16)(acc[g * 8 + j] * inv);
        *(bf16x8*)(dst + g * 8) = w;
    }
}

extern "C" void kernel_launch(void* const* d_in, const int* in_sizes, int n_in,
                              void* d_out, int out_size, void* d_ws, size_t ws_size,
                              hipStream_t stream) {
    const float* x     = (const float*)d_in[0];
    const float* gamma = (const float*)d_in[1];
    const float* beta  = (const float*)d_in[2];
    const float* wqkv  = (const float*)d_in[3];
    const float* wdw   = (const float*)d_in[4];
    const float* bdw   = (const float*)d_in[5];
    const float* wproj = (const float*)d_in[6];
    const float* temp  = (const float*)d_in[7];
    float* out = (float*)d_out;

    char* ws = (char*)d_ws;
    bf16* wqkv_b  = (bf16*)(ws + 0);          // 221184
    bf16* wproj_b = (bf16*)(ws + 221184);     // 73728   -> 294912
    float* mu     = (float*)(ws + 294912);    // 16384   -> 311296
    float* rs     = (float*)(ws + 311296);    // 16384   -> 327680
    bf16* qkv     = (bf16*)(ws + 327680);     // 4718592 -> 5046272
    bf16* qt      = (bf16*)(ws + 5046272);    // 2097152 -> 7143424 (reused as outt)
    bf16* kt      = (bf16*)(ws + 7143424);    // 2097152 -> 9240576
    bf16* vl      = (bf16*)(ws + 9240576);    // 2097152 -> 11337728
    bf16* opart   = (bf16*)(ws + 11337728);   // 12582912 -> 23920640
    bf16* lpart   = (bf16*)(ws + 23920640);   // 524288  -> 24444928
    float* maxk2  = (float*)(ws + 24444928);  // 32
    bf16* outt    = qt;                       // qt dead after flash

    prep<<<448, 256, 0, stream>>>(x, mu, rs, wqkv, wproj, wqkv_b, wproj_b, maxk2);
    gemm192_ln<<<dim3(64, 9), 256, 0, stream>>>(wqkv_b, x, mu, rs, gamma, beta, qkv);
    dwconv<<<1536, 256, 0, stream>>>(qkv, wdw, bdw, qt, kt, vl, maxk2);
    flash_attn<<<NSPLIT * 128, 256, 0, stream>>>(qt, kt, vl, temp, maxk2, opart, lpart);
    combine<<<128, 256, 0, stream>>>(opart, lpart, outt);
    gemm_proj<<<dim3(128, 3), 256, 0, stream>>>(wproj_b, outt, out, x);
}

// Round 9
// 138.340 us; speedup vs baseline: 1.0430x; 1.0430x over previous
//
#include <hip/hip_runtime.h>
#include <hip/hip_bf16.h>

// MDTA: LN -> 1x1 conv (QKV) -> dw3x3 -> spatial attention (N=4096, d=24, 8 heads) -> proj + residual
// Round 9: revert LN-fusion (round-7 prep_ln + gemm192); dwconv q/k stores via LDS transpose
// -> one coalesced b128 store per thread (was 8 scattered b16 stores).

typedef __bf16 bf16;
typedef __bf16 bf16x2 __attribute__((ext_vector_type(2)));
typedef __bf16 bf16x4 __attribute__((ext_vector_type(4)));
typedef __bf16 bf16x8 __attribute__((ext_vector_type(8)));
typedef float f32x4 __attribute__((ext_vector_type(4)));

#define C_DIM 192
#define N_PIX 4096
#define HEADS 8
#define DHEAD 24
#define DPAD 32
#define C3 576
#define NSPLIT 8

__device__ inline float fast_exp2(float x) {
#if __has_builtin(__builtin_amdgcn_exp2f)
    return __builtin_amdgcn_exp2f(x);
#else
    return exp2f(x);
#endif
}

__device__ inline f32x4 mfma16(bf16x8 a, bf16x8 b, f32x4 c) {
    return __builtin_amdgcn_mfma_f32_16x16x32_bf16(a, b, c, 0, 0, 0);
}

// ---------------- merged: LayerNorm (blocks 0..255) + weight prep (blocks 256..687) ----------------
__global__ __launch_bounds__(256) void prep_ln(const float* __restrict__ x,
                                               const float* __restrict__ gamma,
                                               const float* __restrict__ beta,
                                               bf16* __restrict__ xln_t,
                                               const float* __restrict__ wqkv,
                                               const float* __restrict__ wproj,
                                               bf16* __restrict__ wqkv_b,
                                               bf16* __restrict__ wproj_b,
                                               float* __restrict__ maxk2) {
    int b = blockIdx.x, t = threadIdx.x;
    if (b >= 256) {
        int idx = (b - 256) * 256 + t;
        if (idx < C3 * C_DIM) wqkv_b[idx] = (bf16)wqkv[idx];
        if (idx < C_DIM * C_DIM) wproj_b[idx] = (bf16)wproj[idx];
        if (b == 256 && t < 8) maxk2[t] = 0.0f;
        return;
    }
    __shared__ float sred[256], ssred[256];
    int pixg = t & 15, cg = t >> 4;          // 16 pixels x 16 channel-groups of 12
    int p = b * 16 + pixg;
    float v[12];
    float s = 0.f, ss = 0.f;
    for (int j = 0; j < 12; ++j) {
        float f = x[(cg * 12 + j) * N_PIX + p];
        v[j] = f; s += f; ss += f * f;
    }
    sred[t] = s; ssred[t] = ss;
    __syncthreads();
    float S = 0.f, SS = 0.f;
    for (int k = 0; k < 16; ++k) { S += sred[k * 16 + pixg]; SS += ssred[k * 16 + pixg]; }
    float mean = S * (1.0f / C_DIM);
    float var = SS * (1.0f / C_DIM) - mean * mean;
    float rstd = rsqrtf(var + 1e-5f);
    for (int g = 0; g < 3; ++g) {
        bf16x4 w;
        for (int j = 0; j < 4; ++j) {
            int c = cg * 12 + g * 4 + j;
            w[j] = (bf16)((v[g * 4 + j] - mean) * rstd * gamma[c] + beta[c]);
        }
        *(bf16x4*)(xln_t + p * C_DIM + cg * 12 + g * 4) = w;
    }
}

// ---------------- GEMM (64x64 tile): out[M,4096] = A[M,192] * BT[4096,192]^T -> bf16 ----------------
__global__ __launch_bounds__(256) void gemm192(const bf16* __restrict__ A,
                                               const bf16* __restrict__ BT,
                                               bf16* __restrict__ outb) {
    const int K = 192;
    int n0 = blockIdx.x * 64;
    int m0 = blockIdx.y * 64;
    int tid = threadIdx.x;
    int wave = tid >> 6, lane = tid & 63;
    int l16 = lane & 15, quad = lane >> 4;
    int wm = (wave >> 1) * 32, wn = (wave & 1) * 32;
    f32x4 acc[2][2] = {};
    for (int kk = 0; kk < K; kk += 32) {
        bf16x8 a0 = *(const bf16x8*)(A + (m0 + wm + l16) * K + kk + quad * 8);
        bf16x8 a1 = *(const bf16x8*)(A + (m0 + wm + 16 + l16) * K + kk + quad * 8);
        bf16x8 b0 = *(const bf16x8*)(BT + (n0 + wn + l16) * K + kk + quad * 8);
        bf16x8 b1 = *(const bf16x8*)(BT + (n0 + wn + 16 + l16) * K + kk + quad * 8);
        acc[0][0] = mfma16(a0, b0, acc[0][0]);
        acc[0][1] = mfma16(a0, b1, acc[0][1]);
        acc[1][0] = mfma16(a1, b0, acc[1][0]);
        acc[1][1] = mfma16(a1, b1, acc[1][1]);
    }
    for (int i = 0; i < 2; ++i)
        for (int j = 0; j < 2; ++j)
            for (int r = 0; r < 4; ++r) {
                int row = m0 + wm + i * 16 + quad * 4 + r;
                int col = n0 + wn + j * 16 + l16;
                outb[(size_t)row * N_PIX + col] = (bf16)acc[i][j][r];
            }
}

// ---------------- proj GEMM (64m x 32n tile) + fp32 residual epilogue (prefetched) ----------------
__global__ __launch_bounds__(256) void gemm_proj(const bf16* __restrict__ A,
                                                 const bf16* __restrict__ BT,
                                                 float* __restrict__ outf,
                                                 const float* __restrict__ resid) {
    const int K = 192;
    int n0 = blockIdx.x * 32;
    int m0 = blockIdx.y * 64;
    int tid = threadIdx.x;
    int wave = tid >> 6, lane = tid & 63;
    int l16 = lane & 15, quad = lane >> 4;
    int mrow = m0 + wave * 16;
    float rv[8];
    for (int j = 0; j < 2; ++j)
        for (int r = 0; r < 4; ++r)
            rv[j * 4 + r] = resid[(size_t)(mrow + quad * 4 + r) * N_PIX + n0 + j * 16 + l16];
    f32x4 acc[2] = {};
    for (int kk = 0; kk < K; kk += 32) {
        bf16x8 a = *(const bf16x8*)(A + (mrow + l16) * K + kk + quad * 8);
        bf16x8 b0 = *(const bf16x8*)(BT + (n0 + l16) * K + kk + quad * 8);
        bf16x8 b1 = *(const bf16x8*)(BT + (n0 + 16 + l16) * K + kk + quad * 8);
        acc[0] = mfma16(a, b0, acc[0]);
        acc[1] = mfma16(a, b1, acc[1]);
    }
    for (int j = 0; j < 2; ++j)
        for (int r = 0; r < 4; ++r) {
            int row = mrow + quad * 4 + r;
            int col = n0 + j * 16 + l16;
            outf[(size_t)row * N_PIX + col] = acc[j][r] + rv[j * 4 + r];
        }
}

// ---------------- depthwise 3x3 + bias, vectorized; q/k stores via LDS transpose ----------------
// Grid 1536 = part(3) x h(8) x y(64). Thread = (channel 0..23, 8-px segment 0..7).
// part 0/1 (q/k): stage [px][32] tile in LDS (pads included), then 256 coalesced b128 stores
// cover the whole 4KB row. part 2 (v): direct b128 stores (layout already coalesced).
__global__ __launch_bounds__(256) void dwconv(const bf16* __restrict__ qkv,
                                              const float* __restrict__ wdw,
                                              const float* __restrict__ bdw,
                                              bf16* __restrict__ qt,
                                              bf16* __restrict__ kt,
                                              bf16* __restrict__ vl,
                                              float* __restrict__ maxk2) {
    __shared__ float k2s[24][64];
    __shared__ bf16 stg[64 * DPAD];   // [px][ch], 4 KB
    int bx = blockIdx.x;
    int part = bx >> 9;            // 512 blocks per part
    int h = (bx >> 6) & 7;
    int y = bx & 63;
    int t = threadIdx.x;
    int ch_local = t >> 3;         // 0..31 (24 active)
    int seg = t & 7;
    int px0 = seg * 8;
    bool active = ch_local < 24;

    float acc[8];
    if (active) {
        int ch = part * C_DIM + h * DHEAD + ch_local;
        const bf16* in = qkv + (size_t)ch * N_PIX;
        float w[9];
        for (int i = 0; i < 9; ++i) w[i] = wdw[ch * 9 + i];
        float bias = bdw[ch];
        float rowv[3][10];
        for (int r = 0; r < 3; ++r) {
            int yy = y + r - 1;
            if (yy >= 0 && yy < 64) {
                bf16x8 v8 = *(const bf16x8*)(in + yy * 64 + px0);
                for (int j = 0; j < 8; ++j) rowv[r][j + 1] = (float)v8[j];
                rowv[r][0] = (seg > 0) ? (float)in[yy * 64 + px0 - 1] : 0.f;
                rowv[r][9] = (seg < 7) ? (float)in[yy * 64 + px0 + 8] : 0.f;
            } else {
                for (int j = 0; j < 10; ++j) rowv[r][j] = 0.f;
            }
        }
        for (int j = 0; j < 8; ++j) {
            float a = bias;
            for (int r = 0; r < 3; ++r)
                a += w[r * 3 + 0] * rowv[r][j] + w[r * 3 + 1] * rowv[r][j + 1]
                   + w[r * 3 + 2] * rowv[r][j + 2];
            acc[j] = a;
        }
    }

    if (part == 2) {
        if (active) {
            bf16x8 v8;
            for (int j = 0; j < 8; ++j) v8[j] = (bf16)acc[j];
            *(bf16x8*)(vl + ((size_t)(h * DPAD + ch_local)) * N_PIX + y * 64 + px0) = v8;
        } else {
            int i = t - 192;           // pad rows 24..31 x 8 segments
            int dd = 24 + (i >> 3);
            int s2 = i & 7;
            bf16 val = (bf16)((dd == 24) ? 1.0f : 0.0f);
            bf16x8 v8;
            for (int j = 0; j < 8; ++j) v8[j] = val;
            *(bf16x8*)(vl + ((size_t)(h * DPAD + dd)) * N_PIX + y * 64 + s2 * 8) = v8;
        }
    } else {
        if (active) {
            for (int j = 0; j < 8; ++j)
                stg[(px0 + j) * DPAD + ch_local] = (bf16)acc[j];
        } else {
            int i = t - 192;           // px = i: zero pad ch 24..31
            bf16x8 z;
            for (int j = 0; j < 8; ++j) z[j] = (bf16)0.0f;
            *(bf16x8*)(stg + i * DPAD + 24) = z;
        }
        if (part == 1 && active)
            for (int j = 0; j < 8; ++j) k2s[ch_local][px0 + j] = acc[j] * acc[j];
        __syncthreads();
        // coalesced writeback: 256 x b128 covers the full 64px x 32ch row
        bf16* dst = (part == 0 ? qt : kt) + ((size_t)h * N_PIX + y * 64) * DPAD;
        *(bf16x8*)(dst + t * 8) = *(const bf16x8*)(stg + t * 8);
        if (part == 1 && t < 64) {
            float s = 0.f;
            for (int c = 0; c < 24; ++c) s += k2s[c][t];
            for (int off = 1; off < 64; off <<= 1)
                s = fmaxf(s, __shfl_xor(s, off, 64));
            if (t == 0) atomicMax((unsigned int*)(maxk2 + h), __float_as_uint(s));
        }
    }
}

// ---------------- flash attention: fat waves (64 q/wave), no barriers, split-K=8 ----------------
__global__ __launch_bounds__(256, 4) void flash_attn(const bf16* __restrict__ qt,
                                                     const bf16* __restrict__ kt,
                                                     const bf16* __restrict__ vl,
                                                     const float* __restrict__ temp,
                                                     const float* __restrict__ maxk2,
                                                     bf16* __restrict__ opart,
                                                     bf16* __restrict__ lpart) {
    __shared__ __align__(16) bf16 Plds[4 * 4096];   // 8KB per wave: [f(4)][chunk(8)][l16(16)][8]

    int tid = threadIdx.x;
    int wave = tid >> 6, lane = tid & 63;
    int l16 = lane & 15, quad = lane >> 4;
    int head = blockIdx.x & 7;               // block -> XCD round-robin: head pinned per XCD
    int qb = (blockIdx.x >> 3) & 15;
    int split = blockIdx.x >> 7;             // 0..7
    int nbase = qb * 256 + wave * 64;
    float tl = temp[head] * 1.44269504f;

    const bf16* qrow = qt + ((size_t)head * N_PIX + nbase) * DPAD;
    bf16x8 aq[4];
    for (int f = 0; f < 4; ++f)
        aq[f] = *(const bf16x8*)(qrow + (size_t)(f * 16 + l16) * DPAD + quad * 8);

    float mk2 = maxk2[head];
    float Bb[4];
    for (int f = 0; f < 4; ++f) {
        float q2 = 0.f;
        for (int j = 0; j < 8; ++j) { float v = (float)aq[f][j]; q2 += v * v; }
        q2 += __shfl_xor(q2, 16, 64);
        q2 += __shfl_xor(q2, 32, 64);
        Bb[f] = fabsf(tl) * sqrtf(q2 * mk2) + 1.0f;
    }

    const bf16* kbase = kt + (size_t)head * N_PIX * DPAD;
    const bf16* vbase = vl + (size_t)head * DPAD * N_PIX;
    bf16* pw = Plds + wave * 4096;

    f32x4 o0[4] = {}, o1[4] = {};

    #pragma unroll 2
    for (int it = 0; it < 64 / NSPLIT; ++it) {
        int m0 = (split * (64 / NSPLIT) + it) * 64;
        bf16x8 ak[4];
        for (int mt = 0; mt < 4; ++mt)
            ak[mt] = *(const bf16x8*)(kbase + (size_t)(m0 + mt * 16 + l16) * DPAD + quad * 8);
        bf16x8 av[4];
        av[0] = *(const bf16x8*)(vbase + (size_t)l16 * N_PIX + m0 + quad * 8);
        av[1] = *(const bf16x8*)(vbase + (size_t)(16 + l16) * N_PIX + m0 + quad * 8);
        av[2] = *(const bf16x8*)(vbase + (size_t)l16 * N_PIX + m0 + 32 + quad * 8);
        av[3] = *(const bf16x8*)(vbase + (size_t)(16 + l16) * N_PIX + m0 + 32 + quad * 8);

        for (int f = 0; f < 4; ++f) {
            f32x4 z = {0.f, 0.f, 0.f, 0.f};
            f32x4 st[4];
            for (int mt = 0; mt < 4; ++mt) st[mt] = mfma16(ak[mt], aq[f], z);
            for (int mt = 0; mt < 4; ++mt) {
                bf16x4 pk;
                for (int r = 0; r < 4; ++r)
                    pk[r] = (bf16)fast_exp2(__builtin_fmaf(st[mt][r], tl, -Bb[f]));
                int chunk = mt * 2 + (quad >> 1);
                *(bf16x4*)(pw + f * 1024 + (chunk * 16 + l16) * 8 + (quad & 1) * 4) = pk;
            }
        }
        for (int f = 0; f < 4; ++f) {
            bf16x8 ap0 = *(const bf16x8*)(pw + f * 1024 + (quad * 16 + l16) * 8);
            bf16x8 ap1 = *(const bf16x8*)(pw + f * 1024 + ((4 + quad) * 16 + l16) * 8);
            o0[f] = mfma16(av[0], ap0, o0[f]);
            o1[f] = mfma16(av[1], ap0, o1[f]);
            o0[f] = mfma16(av[2], ap1, o0[f]);
            o1[f] = mfma16(av[3], ap1, o1[f]);
        }
    }

    for (int f = 0; f < 4; ++f) {
        int n = nbase + f * 16 + l16;
        size_t rowo = ((size_t)(split * 8 + head) * N_PIX + n) * 24;
        bf16x4 w0;
        for (int r = 0; r < 4; ++r) w0[r] = (bf16)o0[f][r];
        *(bf16x4*)(opart + rowo + quad * 4) = w0;
        if (quad < 2) {
            bf16x4 w1;
            for (int r = 0; r < 4; ++r) w1[r] = (bf16)o1[f][r];
            *(bf16x4*)(opart + rowo + 16 + quad * 4) = w1;
        }
        if (quad == 2)
            lpart[(size_t)(split * 8 + head) * N_PIX + n] = (bf16)o1[f][0];
    }
}

// ---------------- combine split-K partials -> outt[n][c] bf16 (coalesced rows) ----------------
__global__ __launch_bounds__(256) void combine(const bf16* __restrict__ opart,
                                               const bf16* __restrict__ lpart,
                                               bf16* __restrict__ outt) {
    int idx = blockIdx.x * 256 + threadIdx.x;   // 8*4096 threads, one (h,n) row each
    int n = idx & 4095;
    int h = idx >> 12;
    float acc[24];
    for (int j = 0; j < 24; ++j) acc[j] = 0.f;
    float l = 0.f;
    for (int s = 0; s < NSPLIT; ++s) {
        const bf16* row = opart + ((size_t)(s * 8 + h) * N_PIX + n) * 24;
        bf16x8 a = *(const bf16x8*)(row);
        bf16x8 b = *(const bf16x8*)(row + 8);
        bf16x8 c = *(const bf16x8*)(row + 16);
        for (int j = 0; j < 8; ++j) {
            acc[j] += (float)a[j];
            acc[8 + j] += (float)b[j];
            acc[16 + j] += (float)c[j];
        }
        l += (float)lpart[(size_t)(s * 8 + h) * N_PIX + n];
    }
    float inv = 1.0f / l;
    bf16* dst = outt + (size_t)n * C_DIM + h * DHEAD;
    for (int g = 0; g < 3; ++g) {
        bf16x8 w;
        for (int j = 0; j < 8; ++j) w[j] = (bf16)(acc[g * 8 + j] * inv);
        *(bf16x8*)(dst + g * 8) = w;
    }
}

extern "C" void kernel_launch(void* const* d_in, const int* in_sizes, int n_in,
                              void* d_out, int out_size, void* d_ws, size_t ws_size,
                              hipStream_t stream) {
    const float* x     = (const float*)d_in[0];
    const float* gamma = (const float*)d_in[1];
    const float* beta  = (const float*)d_in[2];
    const float* wqkv  = (const float*)d_in[3];
    const float* wdw   = (const float*)d_in[4];
    const float* bdw   = (const float*)d_in[5];
    const float* wproj = (const float*)d_in[6];
    const float* temp  = (const float*)d_in[7];
    float* out = (float*)d_out;

    char* ws = (char*)d_ws;
    bf16* wqkv_b  = (bf16*)(ws + 0);          // 221184
    bf16* wproj_b = (bf16*)(ws + 221184);     // 73728
    bf16* xln     = (bf16*)(ws + 294912);     // 1572864
    bf16* qkv     = (bf16*)(ws + 1867776);    // 4718592
    bf16* qt      = (bf16*)(ws + 6586368);    // 2097152  (reused as outt after flash)
    bf16* kt      = (bf16*)(ws + 8683520);    // 2097152
    bf16* vl      = (bf16*)(ws + 10780672);   // 2097152
    bf16* opart   = (bf16*)(ws + 12877824);   // 8*8*4096*24*2 = 12582912
    bf16* lpart   = (bf16*)(ws + 25460736);   // 8*8*4096*2 = 524288
    float* maxk2  = (float*)(ws + 25985024);  // 32
    bf16* outt    = qt;                       // qt dead after flash

    prep_ln<<<688, 256, 0, stream>>>(x, gamma, beta, xln, wqkv, wproj, wqkv_b, wproj_b, maxk2);
    gemm192<<<dim3(64, 9), 256, 0, stream>>>(wqkv_b, xln, qkv);
    dwconv<<<1536, 256, 0, stream>>>(qkv, wdw, bdw, qt, kt, vl, maxk2);
    flash_attn<<<NSPLIT * 128, 256, 0, stream>>>(qt, kt, vl, temp, maxk2, opart, lpart);
    combine<<<128, 256, 0, stream>>>(opart, lpart, outt);
    gemm_proj<<<dim3(128, 3), 256, 0, stream>>>(wproj_b, outt, out, x);
}

// Round 10
// 135.224 us; speedup vs baseline: 1.0671x; 1.0230x over previous
//
#include <hip/hip_runtime.h>
#include <hip/hip_bf16.h>

// MDTA: LN -> 1x1 conv (QKV) -> dw3x3 -> spatial attention (N=4096, d=24, 8 heads) -> proj + residual
// Round 10: flash S/O phases merged per-fragment (tighter pipe overlap, unroll 4);
// combine fused into gemm_proj via LDS B-panel (5 dispatches total).

typedef __bf16 bf16;
typedef __bf16 bf16x2 __attribute__((ext_vector_type(2)));
typedef __bf16 bf16x4 __attribute__((ext_vector_type(4)));
typedef __bf16 bf16x8 __attribute__((ext_vector_type(8)));
typedef float f32x4 __attribute__((ext_vector_type(4)));

#define C_DIM 192
#define N_PIX 4096
#define HEADS 8
#define DHEAD 24
#define DPAD 32
#define C3 576
#define NSPLIT 8

__device__ inline float fast_exp2(float x) {
#if __has_builtin(__builtin_amdgcn_exp2f)
    return __builtin_amdgcn_exp2f(x);
#else
    return exp2f(x);
#endif
}

__device__ inline f32x4 mfma16(bf16x8 a, bf16x8 b, f32x4 c) {
    return __builtin_amdgcn_mfma_f32_16x16x32_bf16(a, b, c, 0, 0, 0);
}

// ---------------- merged: LayerNorm (blocks 0..255) + weight prep (blocks 256..687) ----------------
__global__ __launch_bounds__(256) void prep_ln(const float* __restrict__ x,
                                               const float* __restrict__ gamma,
                                               const float* __restrict__ beta,
                                               bf16* __restrict__ xln_t,
                                               const float* __restrict__ wqkv,
                                               const float* __restrict__ wproj,
                                               bf16* __restrict__ wqkv_b,
                                               bf16* __restrict__ wproj_b,
                                               float* __restrict__ maxk2) {
    int b = blockIdx.x, t = threadIdx.x;
    if (b >= 256) {
        int idx = (b - 256) * 256 + t;
        if (idx < C3 * C_DIM) wqkv_b[idx] = (bf16)wqkv[idx];
        if (idx < C_DIM * C_DIM) wproj_b[idx] = (bf16)wproj[idx];
        if (b == 256 && t < 8) maxk2[t] = 0.0f;
        return;
    }
    __shared__ float sred[256], ssred[256];
    int pixg = t & 15, cg = t >> 4;          // 16 pixels x 16 channel-groups of 12
    int p = b * 16 + pixg;
    float v[12];
    float s = 0.f, ss = 0.f;
    for (int j = 0; j < 12; ++j) {
        float f = x[(cg * 12 + j) * N_PIX + p];
        v[j] = f; s += f; ss += f * f;
    }
    sred[t] = s; ssred[t] = ss;
    __syncthreads();
    float S = 0.f, SS = 0.f;
    for (int k = 0; k < 16; ++k) { S += sred[k * 16 + pixg]; SS += ssred[k * 16 + pixg]; }
    float mean = S * (1.0f / C_DIM);
    float var = SS * (1.0f / C_DIM) - mean * mean;
    float rstd = rsqrtf(var + 1e-5f);
    for (int g = 0; g < 3; ++g) {
        bf16x4 w;
        for (int j = 0; j < 4; ++j) {
            int c = cg * 12 + g * 4 + j;
            w[j] = (bf16)((v[g * 4 + j] - mean) * rstd * gamma[c] + beta[c]);
        }
        *(bf16x4*)(xln_t + p * C_DIM + cg * 12 + g * 4) = w;
    }
}

// ---------------- GEMM (64x64 tile): out[M,4096] = A[M,192] * BT[4096,192]^T -> bf16 ----------------
__global__ __launch_bounds__(256) void gemm192(const bf16* __restrict__ A,
                                               const bf16* __restrict__ BT,
                                               bf16* __restrict__ outb) {
    const int K = 192;
    int n0 = blockIdx.x * 64;
    int m0 = blockIdx.y * 64;
    int tid = threadIdx.x;
    int wave = tid >> 6, lane = tid & 63;
    int l16 = lane & 15, quad = lane >> 4;
    int wm = (wave >> 1) * 32, wn = (wave & 1) * 32;
    f32x4 acc[2][2] = {};
    for (int kk = 0; kk < K; kk += 32) {
        bf16x8 a0 = *(const bf16x8*)(A + (m0 + wm + l16) * K + kk + quad * 8);
        bf16x8 a1 = *(const bf16x8*)(A + (m0 + wm + 16 + l16) * K + kk + quad * 8);
        bf16x8 b0 = *(const bf16x8*)(BT + (n0 + wn + l16) * K + kk + quad * 8);
        bf16x8 b1 = *(const bf16x8*)(BT + (n0 + wn + 16 + l16) * K + kk + quad * 8);
        acc[0][0] = mfma16(a0, b0, acc[0][0]);
        acc[0][1] = mfma16(a0, b1, acc[0][1]);
        acc[1][0] = mfma16(a1, b0, acc[1][0]);
        acc[1][1] = mfma16(a1, b1, acc[1][1]);
    }
    for (int i = 0; i < 2; ++i)
        for (int j = 0; j < 2; ++j)
            for (int r = 0; r < 4; ++r) {
                int row = m0 + wm + i * 16 + quad * 4 + r;
                int col = n0 + wn + j * 16 + l16;
                outb[(size_t)row * N_PIX + col] = (bf16)acc[i][j][r];
            }
}

// ---------------- proj GEMM with fused split-K combine ----------------
// Block (n0=32 cols, m0=64 rows). Phase 1: 256 threads = (h,nl) combine 8 split partials for
// row (h, n0+nl) -> LDS B-panel [nl][c] (stride 200 elems to break bank alignment).
// Phase 2: standard MFMA GEMM, B-fragments from LDS, fp32 residual epilogue.
__global__ __launch_bounds__(256) void gemm_proj(const bf16* __restrict__ A,
                                                 const bf16* __restrict__ opart,
                                                 const bf16* __restrict__ lpart,
                                                 float* __restrict__ outf,
                                                 const float* __restrict__ resid) {
    __shared__ __align__(16) bf16 Bld[32 * 200];
    const int K = 192;
    int n0 = blockIdx.x * 32;
    int m0 = blockIdx.y * 64;
    int t = threadIdx.x;
    {
        int h = t >> 5, nl = t & 31;
        int n = n0 + nl;
        float acc[24];
        for (int j = 0; j < 24; ++j) acc[j] = 0.f;
        float l = 0.f;
        for (int s = 0; s < NSPLIT; ++s) {
            const bf16* row = opart + ((size_t)(s * 8 + h) * N_PIX + n) * 24;
            bf16x8 a = *(const bf16x8*)(row);
            bf16x8 b = *(const bf16x8*)(row + 8);
            bf16x8 c = *(const bf16x8*)(row + 16);
            for (int j = 0; j < 8; ++j) {
                acc[j] += (float)a[j];
                acc[8 + j] += (float)b[j];
                acc[16 + j] += (float)c[j];
            }
            l += (float)lpart[(size_t)(s * 8 + h) * N_PIX + n];
        }
        float inv = 1.0f / l;
        bf16* dst = Bld + nl * 200 + h * 24;
        for (int g = 0; g < 3; ++g) {
            bf16x8 w;
            for (int j = 0; j < 8; ++j) w[j] = (bf16)(acc[g * 8 + j] * inv);
            *(bf16x8*)(dst + g * 8) = w;
        }
    }
    __syncthreads();
    int wave = t >> 6, lane = t & 63;
    int l16 = lane & 15, quad = lane >> 4;
    int mrow = m0 + wave * 16;
    float rv[8];
    for (int j = 0; j < 2; ++j)
        for (int r = 0; r < 4; ++r)
            rv[j * 4 + r] = resid[(size_t)(mrow + quad * 4 + r) * N_PIX + n0 + j * 16 + l16];
    f32x4 acc2[2] = {};
    for (int kk = 0; kk < K; kk += 32) {
        bf16x8 a = *(const bf16x8*)(A + (mrow + l16) * K + kk + quad * 8);
        bf16x8 b0 = *(const bf16x8*)(Bld + l16 * 200 + kk + quad * 8);
        bf16x8 b1 = *(const bf16x8*)(Bld + (16 + l16) * 200 + kk + quad * 8);
        acc2[0] = mfma16(a, b0, acc2[0]);
        acc2[1] = mfma16(a, b1, acc2[1]);
    }
    for (int j = 0; j < 2; ++j)
        for (int r = 0; r < 4; ++r) {
            int row = mrow + quad * 4 + r;
            int col = n0 + j * 16 + l16;
            outf[(size_t)row * N_PIX + col] = acc2[j][r] + rv[j * 4 + r];
        }
}

// ---------------- depthwise 3x3 + bias, vectorized; q/k stores via LDS transpose ----------------
__global__ __launch_bounds__(256) void dwconv(const bf16* __restrict__ qkv,
                                              const float* __restrict__ wdw,
                                              const float* __restrict__ bdw,
                                              bf16* __restrict__ qt,
                                              bf16* __restrict__ kt,
                                              bf16* __restrict__ vl,
                                              float* __restrict__ maxk2) {
    __shared__ float k2s[24][64];
    __shared__ bf16 stg[64 * DPAD];   // [px][ch], 4 KB
    int bx = blockIdx.x;
    int part = bx >> 9;            // 512 blocks per part
    int h = (bx >> 6) & 7;
    int y = bx & 63;
    int t = threadIdx.x;
    int ch_local = t >> 3;         // 0..31 (24 active)
    int seg = t & 7;
    int px0 = seg * 8;
    bool active = ch_local < 24;

    float acc[8];
    if (active) {
        int ch = part * C_DIM + h * DHEAD + ch_local;
        const bf16* in = qkv + (size_t)ch * N_PIX;
        float w[9];
        for (int i = 0; i < 9; ++i) w[i] = wdw[ch * 9 + i];
        float bias = bdw[ch];
        float rowv[3][10];
        for (int r = 0; r < 3; ++r) {
            int yy = y + r - 1;
            if (yy >= 0 && yy < 64) {
                bf16x8 v8 = *(const bf16x8*)(in + yy * 64 + px0);
                for (int j = 0; j < 8; ++j) rowv[r][j + 1] = (float)v8[j];
                rowv[r][0] = (seg > 0) ? (float)in[yy * 64 + px0 - 1] : 0.f;
                rowv[r][9] = (seg < 7) ? (float)in[yy * 64 + px0 + 8] : 0.f;
            } else {
                for (int j = 0; j < 10; ++j) rowv[r][j] = 0.f;
            }
        }
        for (int j = 0; j < 8; ++j) {
            float a = bias;
            for (int r = 0; r < 3; ++r)
                a += w[r * 3 + 0] * rowv[r][j] + w[r * 3 + 1] * rowv[r][j + 1]
                   + w[r * 3 + 2] * rowv[r][j + 2];
            acc[j] = a;
        }
    }

    if (part == 2) {
        if (active) {
            bf16x8 v8;
            for (int j = 0; j < 8; ++j) v8[j] = (bf16)acc[j];
            *(bf16x8*)(vl + ((size_t)(h * DPAD + ch_local)) * N_PIX + y * 64 + px0) = v8;
        } else {
            int i = t - 192;           // pad rows 24..31 x 8 segments
            int dd = 24 + (i >> 3);
            int s2 = i & 7;
            bf16 val = (bf16)((dd == 24) ? 1.0f : 0.0f);
            bf16x8 v8;
            for (int j = 0; j < 8; ++j) v8[j] = val;
            *(bf16x8*)(vl + ((size_t)(h * DPAD + dd)) * N_PIX + y * 64 + s2 * 8) = v8;
        }
    } else {
        if (active) {
            for (int j = 0; j < 8; ++j)
                stg[(px0 + j) * DPAD + ch_local] = (bf16)acc[j];
        } else {
            int i = t - 192;           // px = i: zero pad ch 24..31
            bf16x8 z;
            for (int j = 0; j < 8; ++j) z[j] = (bf16)0.0f;
            *(bf16x8*)(stg + i * DPAD + 24) = z;
        }
        if (part == 1 && active)
            for (int j = 0; j < 8; ++j) k2s[ch_local][px0 + j] = acc[j] * acc[j];
        __syncthreads();
        bf16* dst = (part == 0 ? qt : kt) + ((size_t)h * N_PIX + y * 64) * DPAD;
        *(bf16x8*)(dst + t * 8) = *(const bf16x8*)(stg + t * 8);
        if (part == 1 && t < 64) {
            float s = 0.f;
            for (int c = 0; c < 24; ++c) s += k2s[c][t];
            for (int off = 1; off < 64; off <<= 1)
                s = fmaxf(s, __shfl_xor(s, off, 64));
            if (t == 0) atomicMax((unsigned int*)(maxk2 + h), __float_as_uint(s));
        }
    }
}

// ---------------- flash attention: fat waves, merged S/O per fragment, split-K=8 ----------------
// Per key-tile iter, per q-fragment f: 4 S^T MFMAs -> exp2 -> P write (b64) -> P read (b128)
// -> 4 O^T MFMAs. Same-wave DS ops are in-order, so the P round-trip needs no barrier.
// No barriers anywhere in the K-loop; unroll 4 lets global loads hoist across iterations.
__global__ __launch_bounds__(256, 4) void flash_attn(const bf16* __restrict__ qt,
                                                     const bf16* __restrict__ kt,
                                                     const bf16* __restrict__ vl,
                                                     const float* __restrict__ temp,
                                                     const float* __restrict__ maxk2,
                                                     bf16* __restrict__ opart,
                                                     bf16* __restrict__ lpart) {
    __shared__ __align__(16) bf16 Plds[4 * 4096];   // 8KB per wave: [f(4)][chunk(8)][l16(16)][8]

    int tid = threadIdx.x;
    int wave = tid >> 6, lane = tid & 63;
    int l16 = lane & 15, quad = lane >> 4;
    int head = blockIdx.x & 7;               // block -> XCD round-robin: head pinned per XCD
    int qb = (blockIdx.x >> 3) & 15;
    int split = blockIdx.x >> 7;             // 0..7
    int nbase = qb * 256 + wave * 64;
    float tl = temp[head] * 1.44269504f;

    const bf16* qrow = qt + ((size_t)head * N_PIX + nbase) * DPAD;
    bf16x8 aq[4];
    for (int f = 0; f < 4; ++f)
        aq[f] = *(const bf16x8*)(qrow + (size_t)(f * 16 + l16) * DPAD + quad * 8);

    float mk2 = maxk2[head];
    float Bb[4];
    for (int f = 0; f < 4; ++f) {
        float q2 = 0.f;
        for (int j = 0; j < 8; ++j) { float v = (float)aq[f][j]; q2 += v * v; }
        q2 += __shfl_xor(q2, 16, 64);
        q2 += __shfl_xor(q2, 32, 64);
        Bb[f] = fabsf(tl) * sqrtf(q2 * mk2) + 1.0f;
    }

    const bf16* kbase = kt + (size_t)head * N_PIX * DPAD;
    const bf16* vbase = vl + (size_t)head * DPAD * N_PIX;
    bf16* pw = Plds + wave * 4096;

    f32x4 o0[4] = {}, o1[4] = {};

    #pragma unroll 4
    for (int it = 0; it < 64 / NSPLIT; ++it) {
        int m0 = (split * (64 / NSPLIT) + it) * 64;
        bf16x8 ak[4];
        for (int mt = 0; mt < 4; ++mt)
            ak[mt] = *(const bf16x8*)(kbase + (size_t)(m0 + mt * 16 + l16) * DPAD + quad * 8);
        bf16x8 av[4];
        av[0] = *(const bf16x8*)(vbase + (size_t)l16 * N_PIX + m0 + quad * 8);
        av[1] = *(const bf16x8*)(vbase + (size_t)(16 + l16) * N_PIX + m0 + quad * 8);
        av[2] = *(const bf16x8*)(vbase + (size_t)l16 * N_PIX + m0 + 32 + quad * 8);
        av[3] = *(const bf16x8*)(vbase + (size_t)(16 + l16) * N_PIX + m0 + 32 + quad * 8);

        for (int f = 0; f < 4; ++f) {
            f32x4 z = {0.f, 0.f, 0.f, 0.f};
            f32x4 st[4];
            for (int mt = 0; mt < 4; ++mt) st[mt] = mfma16(ak[mt], aq[f], z);
            for (int mt = 0; mt < 4; ++mt) {
                bf16x4 pk;
                for (int r = 0; r < 4; ++r)
                    pk[r] = (bf16)fast_exp2(__builtin_fmaf(st[mt][r], tl, -Bb[f]));
                int chunk = mt * 2 + (quad >> 1);
                *(bf16x4*)(pw + f * 1024 + (chunk * 16 + l16) * 8 + (quad & 1) * 4) = pk;
            }
            bf16x8 ap0 = *(const bf16x8*)(pw + f * 1024 + (quad * 16 + l16) * 8);
            bf16x8 ap1 = *(const bf16x8*)(pw + f * 1024 + ((4 + quad) * 16 + l16) * 8);
            o0[f] = mfma16(av[0], ap0, o0[f]);
            o1[f] = mfma16(av[1], ap0, o1[f]);
            o0[f] = mfma16(av[2], ap1, o0[f]);
            o1[f] = mfma16(av[3], ap1, o1[f]);
        }
    }

    for (int f = 0; f < 4; ++f) {
        int n = nbase + f * 16 + l16;
        size_t rowo = ((size_t)(split * 8 + head) * N_PIX + n) * 24;
        bf16x4 w0;
        for (int r = 0; r < 4; ++r) w0[r] = (bf16)o0[f][r];
        *(bf16x4*)(opart + rowo + quad * 4) = w0;
        if (quad < 2) {
            bf16x4 w1;
            for (int r = 0; r < 4; ++r) w1[r] = (bf16)o1[f][r];
            *(bf16x4*)(opart + rowo + 16 + quad * 4) = w1;
        }
        if (quad == 2)
            lpart[(size_t)(split * 8 + head) * N_PIX + n] = (bf16)o1[f][0];
    }
}

extern "C" void kernel_launch(void* const* d_in, const int* in_sizes, int n_in,
                              void* d_out, int out_size, void* d_ws, size_t ws_size,
                              hipStream_t stream) {
    const float* x     = (const float*)d_in[0];
    const float* gamma = (const float*)d_in[1];
    const float* beta  = (const float*)d_in[2];
    const float* wqkv  = (const float*)d_in[3];
    const float* wdw   = (const float*)d_in[4];
    const float* bdw   = (const float*)d_in[5];
    const float* wproj = (const float*)d_in[6];
    const float* temp  = (const float*)d_in[7];
    float* out = (float*)d_out;

    char* ws = (char*)d_ws;
    bf16* wqkv_b  = (bf16*)(ws + 0);          // 221184
    bf16* wproj_b = (bf16*)(ws + 221184);     // 73728
    bf16* xln     = (bf16*)(ws + 294912);     // 1572864
    bf16* qkv     = (bf16*)(ws + 1867776);    // 4718592
    bf16* qt      = (bf16*)(ws + 6586368);    // 2097152
    bf16* kt      = (bf16*)(ws + 8683520);    // 2097152
    bf16* vl      = (bf16*)(ws + 10780672);   // 2097152
    bf16* opart   = (bf16*)(ws + 12877824);   // 8*8*4096*24*2 = 12582912
    bf16* lpart   = (bf16*)(ws + 25460736);   // 8*8*4096*2 = 524288
    float* maxk2  = (float*)(ws + 25985024);  // 32

    prep_ln<<<688, 256, 0, stream>>>(x, gamma, beta, xln, wqkv, wproj, wqkv_b, wproj_b, maxk2);
    gemm192<<<dim3(64, 9), 256, 0, stream>>>(wqkv_b, xln, qkv);
    dwconv<<<1536, 256, 0, stream>>>(qkv, wdw, bdw, qt, kt, vl, maxk2);
    flash_attn<<<NSPLIT * 128, 256, 0, stream>>>(qt, kt, vl, temp, maxk2, opart, lpart);
    gemm_proj<<<dim3(128, 3), 256, 0, stream>>>(wproj_b, opart, lpart, out, x);
}

// Round 11
// 133.520 us; speedup vs baseline: 1.0807x; 1.0128x over previous
//
#include <hip/hip_runtime.h>
#include <hip/hip_bf16.h>

// MDTA: LN -> 1x1 conv (QKV) -> dw3x3 -> spatial attention (N=4096, d=24, 8 heads) -> proj + residual
// Round 11: flash software-pipelined — K-fragments prefetched one iter ahead (fits 128 VGPR),
// Plds shrunk to 2KB/wave (single region reused across q-fragments; same-wave DS in-order).

typedef __bf16 bf16;
typedef __bf16 bf16x2 __attribute__((ext_vector_type(2)));
typedef __bf16 bf16x4 __attribute__((ext_vector_type(4)));
typedef __bf16 bf16x8 __attribute__((ext_vector_type(8)));
typedef float f32x4 __attribute__((ext_vector_type(4)));

#define C_DIM 192
#define N_PIX 4096
#define HEADS 8
#define DHEAD 24
#define DPAD 32
#define C3 576
#define NSPLIT 8

__device__ inline float fast_exp2(float x) {
#if __has_builtin(__builtin_amdgcn_exp2f)
    return __builtin_amdgcn_exp2f(x);
#else
    return exp2f(x);
#endif
}

__device__ inline f32x4 mfma16(bf16x8 a, bf16x8 b, f32x4 c) {
    return __builtin_amdgcn_mfma_f32_16x16x32_bf16(a, b, c, 0, 0, 0);
}

// ---------------- merged: LayerNorm (blocks 0..255) + weight prep (blocks 256..687) ----------------
__global__ __launch_bounds__(256) void prep_ln(const float* __restrict__ x,
                                               const float* __restrict__ gamma,
                                               const float* __restrict__ beta,
                                               bf16* __restrict__ xln_t,
                                               const float* __restrict__ wqkv,
                                               const float* __restrict__ wproj,
                                               bf16* __restrict__ wqkv_b,
                                               bf16* __restrict__ wproj_b,
                                               float* __restrict__ maxk2) {
    int b = blockIdx.x, t = threadIdx.x;
    if (b >= 256) {
        int idx = (b - 256) * 256 + t;
        if (idx < C3 * C_DIM) wqkv_b[idx] = (bf16)wqkv[idx];
        if (idx < C_DIM * C_DIM) wproj_b[idx] = (bf16)wproj[idx];
        if (b == 256 && t < 8) maxk2[t] = 0.0f;
        return;
    }
    __shared__ float sred[256], ssred[256];
    int pixg = t & 15, cg = t >> 4;          // 16 pixels x 16 channel-groups of 12
    int p = b * 16 + pixg;
    float v[12];
    float s = 0.f, ss = 0.f;
    for (int j = 0; j < 12; ++j) {
        float f = x[(cg * 12 + j) * N_PIX + p];
        v[j] = f; s += f; ss += f * f;
    }
    sred[t] = s; ssred[t] = ss;
    __syncthreads();
    float S = 0.f, SS = 0.f;
    for (int k = 0; k < 16; ++k) { S += sred[k * 16 + pixg]; SS += ssred[k * 16 + pixg]; }
    float mean = S * (1.0f / C_DIM);
    float var = SS * (1.0f / C_DIM) - mean * mean;
    float rstd = rsqrtf(var + 1e-5f);
    for (int g = 0; g < 3; ++g) {
        bf16x4 w;
        for (int j = 0; j < 4; ++j) {
            int c = cg * 12 + g * 4 + j;
            w[j] = (bf16)((v[g * 4 + j] - mean) * rstd * gamma[c] + beta[c]);
        }
        *(bf16x4*)(xln_t + p * C_DIM + cg * 12 + g * 4) = w;
    }
}

// ---------------- GEMM (64x64 tile): out[M,4096] = A[M,192] * BT[4096,192]^T -> bf16 ----------------
__global__ __launch_bounds__(256) void gemm192(const bf16* __restrict__ A,
                                               const bf16* __restrict__ BT,
                                               bf16* __restrict__ outb) {
    const int K = 192;
    int n0 = blockIdx.x * 64;
    int m0 = blockIdx.y * 64;
    int tid = threadIdx.x;
    int wave = tid >> 6, lane = tid & 63;
    int l16 = lane & 15, quad = lane >> 4;
    int wm = (wave >> 1) * 32, wn = (wave & 1) * 32;
    f32x4 acc[2][2] = {};
    for (int kk = 0; kk < K; kk += 32) {
        bf16x8 a0 = *(const bf16x8*)(A + (m0 + wm + l16) * K + kk + quad * 8);
        bf16x8 a1 = *(const bf16x8*)(A + (m0 + wm + 16 + l16) * K + kk + quad * 8);
        bf16x8 b0 = *(const bf16x8*)(BT + (n0 + wn + l16) * K + kk + quad * 8);
        bf16x8 b1 = *(const bf16x8*)(BT + (n0 + wn + 16 + l16) * K + kk + quad * 8);
        acc[0][0] = mfma16(a0, b0, acc[0][0]);
        acc[0][1] = mfma16(a0, b1, acc[0][1]);
        acc[1][0] = mfma16(a1, b0, acc[1][0]);
        acc[1][1] = mfma16(a1, b1, acc[1][1]);
    }
    for (int i = 0; i < 2; ++i)
        for (int j = 0; j < 2; ++j)
            for (int r = 0; r < 4; ++r) {
                int row = m0 + wm + i * 16 + quad * 4 + r;
                int col = n0 + wn + j * 16 + l16;
                outb[(size_t)row * N_PIX + col] = (bf16)acc[i][j][r];
            }
}

// ---------------- proj GEMM with fused split-K combine ----------------
__global__ __launch_bounds__(256) void gemm_proj(const bf16* __restrict__ A,
                                                 const bf16* __restrict__ opart,
                                                 const bf16* __restrict__ lpart,
                                                 float* __restrict__ outf,
                                                 const float* __restrict__ resid) {
    __shared__ __align__(16) bf16 Bld[32 * 200];
    const int K = 192;
    int n0 = blockIdx.x * 32;
    int m0 = blockIdx.y * 64;
    int t = threadIdx.x;
    {
        int h = t >> 5, nl = t & 31;
        int n = n0 + nl;
        float acc[24];
        for (int j = 0; j < 24; ++j) acc[j] = 0.f;
        float l = 0.f;
        for (int s = 0; s < NSPLIT; ++s) {
            const bf16* row = opart + ((size_t)(s * 8 + h) * N_PIX + n) * 24;
            bf16x8 a = *(const bf16x8*)(row);
            bf16x8 b = *(const bf16x8*)(row + 8);
            bf16x8 c = *(const bf16x8*)(row + 16);
            for (int j = 0; j < 8; ++j) {
                acc[j] += (float)a[j];
                acc[8 + j] += (float)b[j];
                acc[16 + j] += (float)c[j];
            }
            l += (float)lpart[(size_t)(s * 8 + h) * N_PIX + n];
        }
        float inv = 1.0f / l;
        bf16* dst = Bld + nl * 200 + h * 24;
        for (int g = 0; g < 3; ++g) {
            bf16x8 w;
            for (int j = 0; j < 8; ++j) w[j] = (bf16)(acc[g * 8 + j] * inv);
            *(bf16x8*)(dst + g * 8) = w;
        }
    }
    __syncthreads();
    int wave = t >> 6, lane = t & 63;
    int l16 = lane & 15, quad = lane >> 4;
    int mrow = m0 + wave * 16;
    float rv[8];
    for (int j = 0; j < 2; ++j)
        for (int r = 0; r < 4; ++r)
            rv[j * 4 + r] = resid[(size_t)(mrow + quad * 4 + r) * N_PIX + n0 + j * 16 + l16];
    f32x4 acc2[2] = {};
    for (int kk = 0; kk < K; kk += 32) {
        bf16x8 a = *(const bf16x8*)(A + (mrow + l16) * K + kk + quad * 8);
        bf16x8 b0 = *(const bf16x8*)(Bld + l16 * 200 + kk + quad * 8);
        bf16x8 b1 = *(const bf16x8*)(Bld + (16 + l16) * 200 + kk + quad * 8);
        acc2[0] = mfma16(a, b0, acc2[0]);
        acc2[1] = mfma16(a, b1, acc2[1]);
    }
    for (int j = 0; j < 2; ++j)
        for (int r = 0; r < 4; ++r) {
            int row = mrow + quad * 4 + r;
            int col = n0 + j * 16 + l16;
            outf[(size_t)row * N_PIX + col] = acc2[j][r] + rv[j * 4 + r];
        }
}

// ---------------- depthwise 3x3 + bias, vectorized; q/k stores via LDS transpose ----------------
__global__ __launch_bounds__(256) void dwconv(const bf16* __restrict__ qkv,
                                              const float* __restrict__ wdw,
                                              const float* __restrict__ bdw,
                                              bf16* __restrict__ qt,
                                              bf16* __restrict__ kt,
                                              bf16* __restrict__ vl,
                                              float* __restrict__ maxk2) {
    __shared__ float k2s[24][64];
    __shared__ bf16 stg[64 * DPAD];   // [px][ch], 4 KB
    int bx = blockIdx.x;
    int part = bx >> 9;            // 512 blocks per part
    int h = (bx >> 6) & 7;
    int y = bx & 63;
    int t = threadIdx.x;
    int ch_local = t >> 3;         // 0..31 (24 active)
    int seg = t & 7;
    int px0 = seg * 8;
    bool active = ch_local < 24;

    float acc[8];
    if (active) {
        int ch = part * C_DIM + h * DHEAD + ch_local;
        const bf16* in = qkv + (size_t)ch * N_PIX;
        float w[9];
        for (int i = 0; i < 9; ++i) w[i] = wdw[ch * 9 + i];
        float bias = bdw[ch];
        float rowv[3][10];
        for (int r = 0; r < 3; ++r) {
            int yy = y + r - 1;
            if (yy >= 0 && yy < 64) {
                bf16x8 v8 = *(const bf16x8*)(in + yy * 64 + px0);
                for (int j = 0; j < 8; ++j) rowv[r][j + 1] = (float)v8[j];
                rowv[r][0] = (seg > 0) ? (float)in[yy * 64 + px0 - 1] : 0.f;
                rowv[r][9] = (seg < 7) ? (float)in[yy * 64 + px0 + 8] : 0.f;
            } else {
                for (int j = 0; j < 10; ++j) rowv[r][j] = 0.f;
            }
        }
        for (int j = 0; j < 8; ++j) {
            float a = bias;
            for (int r = 0; r < 3; ++r)
                a += w[r * 3 + 0] * rowv[r][j] + w[r * 3 + 1] * rowv[r][j + 1]
                   + w[r * 3 + 2] * rowv[r][j + 2];
            acc[j] = a;
        }
    }

    if (part == 2) {
        if (active) {
            bf16x8 v8;
            for (int j = 0; j < 8; ++j) v8[j] = (bf16)acc[j];
            *(bf16x8*)(vl + ((size_t)(h * DPAD + ch_local)) * N_PIX + y * 64 + px0) = v8;
        } else {
            int i = t - 192;           // pad rows 24..31 x 8 segments
            int dd = 24 + (i >> 3);
            int s2 = i & 7;
            bf16 val = (bf16)((dd == 24) ? 1.0f : 0.0f);
            bf16x8 v8;
            for (int j = 0; j < 8; ++j) v8[j] = val;
            *(bf16x8*)(vl + ((size_t)(h * DPAD + dd)) * N_PIX + y * 64 + s2 * 8) = v8;
        }
    } else {
        if (active) {
            for (int j = 0; j < 8; ++j)
                stg[(px0 + j) * DPAD + ch_local] = (bf16)acc[j];
        } else {
            int i = t - 192;           // px = i: zero pad ch 24..31
            bf16x8 z;
            for (int j = 0; j < 8; ++j) z[j] = (bf16)0.0f;
            *(bf16x8*)(stg + i * DPAD + 24) = z;
        }
        if (part == 1 && active)
            for (int j = 0; j < 8; ++j) k2s[ch_local][px0 + j] = acc[j] * acc[j];
        __syncthreads();
        bf16* dst = (part == 0 ? qt : kt) + ((size_t)h * N_PIX + y * 64) * DPAD;
        *(bf16x8*)(dst + t * 8) = *(const bf16x8*)(stg + t * 8);
        if (part == 1 && t < 64) {
            float s = 0.f;
            for (int c = 0; c < 24; ++c) s += k2s[c][t];
            for (int off = 1; off < 64; off <<= 1)
                s = fmaxf(s, __shfl_xor(s, off, 64));
            if (t == 0) atomicMax((unsigned int*)(maxk2 + h), __float_as_uint(s));
        }
    }
}

// ---------------- flash attention: fat waves, K-prefetch pipeline, split-K=8 ----------------
// Per key-tile iter: V loads issued at top (self-hiding: first consumed ~150cyc later),
// next iter's K fragments prefetched into akn (the exposed loads), then per q-fragment:
// 4 S^T MFMAs -> exp2 -> P write (b64) -> P read (b128) -> 4 O^T MFMAs.
// Plds is 2KB/wave, REUSED across fragments — same-wave DS ops are in-order and the
// addresses alias, so write(f+1) cannot pass read(f). No barriers anywhere.
__global__ __launch_bounds__(256, 4) void flash_attn(const bf16* __restrict__ qt,
                                                     const bf16* __restrict__ kt,
                                                     const bf16* __restrict__ vl,
                                                     const float* __restrict__ temp,
                                                     const float* __restrict__ maxk2,
                                                     bf16* __restrict__ opart,
                                                     bf16* __restrict__ lpart) {
    __shared__ __align__(16) bf16 Plds[4 * 1024];   // 2KB per wave: [chunk(8)][l16(16)][8]

    int tid = threadIdx.x;
    int wave = tid >> 6, lane = tid & 63;
    int l16 = lane & 15, quad = lane >> 4;
    int head = blockIdx.x & 7;               // block -> XCD round-robin: head pinned per XCD
    int qb = (blockIdx.x >> 3) & 15;
    int split = blockIdx.x >> 7;             // 0..7
    int nbase = qb * 256 + wave * 64;
    float tl = temp[head] * 1.44269504f;

    const bf16* qrow = qt + ((size_t)head * N_PIX + nbase) * DPAD;
    bf16x8 aq[4];
    for (int f = 0; f < 4; ++f)
        aq[f] = *(const bf16x8*)(qrow + (size_t)(f * 16 + l16) * DPAD + quad * 8);

    float mk2 = maxk2[head];
    float Bb[4];
    for (int f = 0; f < 4; ++f) {
        float q2 = 0.f;
        for (int j = 0; j < 8; ++j) { float v = (float)aq[f][j]; q2 += v * v; }
        q2 += __shfl_xor(q2, 16, 64);
        q2 += __shfl_xor(q2, 32, 64);
        Bb[f] = fabsf(tl) * sqrtf(q2 * mk2) + 1.0f;
    }

    const bf16* kbase = kt + (size_t)head * N_PIX * DPAD;
    const bf16* vbase = vl + (size_t)head * DPAD * N_PIX;
    bf16* pw = Plds + wave * 1024;

    f32x4 o0[4] = {}, o1[4] = {};

    const int NITER = 64 / NSPLIT;           // 8
    int mbase = split * NITER * 64;

    // prologue: K fragments for iter 0
    bf16x8 ak[4];
    for (int mt = 0; mt < 4; ++mt)
        ak[mt] = *(const bf16x8*)(kbase + (size_t)(mbase + mt * 16 + l16) * DPAD + quad * 8);

    #pragma unroll 2
    for (int it = 0; it < NITER; ++it) {
        int m0 = mbase + it * 64;
        // V fragments for this iter (consumed late -> latency self-hiding)
        bf16x8 av0 = *(const bf16x8*)(vbase + (size_t)l16 * N_PIX + m0 + quad * 8);
        bf16x8 av1 = *(const bf16x8*)(vbase + (size_t)(16 + l16) * N_PIX + m0 + quad * 8);
        bf16x8 av2 = *(const bf16x8*)(vbase + (size_t)l16 * N_PIX + m0 + 32 + quad * 8);
        bf16x8 av3 = *(const bf16x8*)(vbase + (size_t)(16 + l16) * N_PIX + m0 + 32 + quad * 8);
        // prefetch next iter's K fragments (the latency-exposed loads)
        bf16x8 akn[4];
        if (it + 1 < NITER) {
            int m1 = m0 + 64;
            for (int mt = 0; mt < 4; ++mt)
                akn[mt] = *(const bf16x8*)(kbase + (size_t)(m1 + mt * 16 + l16) * DPAD + quad * 8);
        }

        for (int f = 0; f < 4; ++f) {
            f32x4 z = {0.f, 0.f, 0.f, 0.f};
            f32x4 st[4];
            for (int mt = 0; mt < 4; ++mt) st[mt] = mfma16(ak[mt], aq[f], z);
            for (int mt = 0; mt < 4; ++mt) {
                bf16x4 pk;
                for (int r = 0; r < 4; ++r)
                    pk[r] = (bf16)fast_exp2(__builtin_fmaf(st[mt][r], tl, -Bb[f]));
                int chunk = mt * 2 + (quad >> 1);
                *(bf16x4*)(pw + (chunk * 16 + l16) * 8 + (quad & 1) * 4) = pk;
            }
            bf16x8 ap0 = *(const bf16x8*)(pw + (quad * 16 + l16) * 8);
            bf16x8 ap1 = *(const bf16x8*)(pw + ((4 + quad) * 16 + l16) * 8);
            o0[f] = mfma16(av0, ap0, o0[f]);
            o1[f] = mfma16(av1, ap0, o1[f]);
            o0[f] = mfma16(av2, ap1, o0[f]);
            o1[f] = mfma16(av3, ap1, o1[f]);
        }
        if (it + 1 < NITER)
            for (int mt = 0; mt < 4; ++mt) ak[mt] = akn[mt];
    }

    for (int f = 0; f < 4; ++f) {
        int n = nbase + f * 16 + l16;
        size_t rowo = ((size_t)(split * 8 + head) * N_PIX + n) * 24;
        bf16x4 w0;
        for (int r = 0; r < 4; ++r) w0[r] = (bf16)o0[f][r];
        *(bf16x4*)(opart + rowo + quad * 4) = w0;
        if (quad < 2) {
            bf16x4 w1;
            for (int r = 0; r < 4; ++r) w1[r] = (bf16)o1[f][r];
            *(bf16x4*)(opart + rowo + 16 + quad * 4) = w1;
        }
        if (quad == 2)
            lpart[(size_t)(split * 8 + head) * N_PIX + n] = (bf16)o1[f][0];
    }
}

extern "C" void kernel_launch(void* const* d_in, const int* in_sizes, int n_in,
                              void* d_out, int out_size, void* d_ws, size_t ws_size,
                              hipStream_t stream) {
    const float* x     = (const float*)d_in[0];
    const float* gamma = (const float*)d_in[1];
    const float* beta  = (const float*)d_in[2];
    const float* wqkv  = (const float*)d_in[3];
    const float* wdw   = (const float*)d_in[4];
    const float* bdw   = (const float*)d_in[5];
    const float* wproj = (const float*)d_in[6];
    const float* temp  = (const float*)d_in[7];
    float* out = (float*)d_out;

    char* ws = (char*)d_ws;
    bf16* wqkv_b  = (bf16*)(ws + 0);          // 221184
    bf16* wproj_b = (bf16*)(ws + 221184);     // 73728
    bf16* xln     = (bf16*)(ws + 294912);     // 1572864
    bf16* qkv     = (bf16*)(ws + 1867776);    // 4718592
    bf16* qt      = (bf16*)(ws + 6586368);    // 2097152
    bf16* kt      = (bf16*)(ws + 8683520);    // 2097152
    bf16* vl      = (bf16*)(ws + 10780672);   // 2097152
    bf16* opart   = (bf16*)(ws + 12877824);   // 8*8*4096*24*2 = 12582912
    bf16* lpart   = (bf16*)(ws + 25460736);   // 8*8*4096*2 = 524288
    float* maxk2  = (float*)(ws + 25985024);  // 32

    prep_ln<<<688, 256, 0, stream>>>(x, gamma, beta, xln, wqkv, wproj, wqkv_b, wproj_b, maxk2);
    gemm192<<<dim3(64, 9), 256, 0, stream>>>(wqkv_b, xln, qkv);
    dwconv<<<1536, 256, 0, stream>>>(qkv, wdw, bdw, qt, kt, vl, maxk2);
    flash_attn<<<NSPLIT * 128, 256, 0, stream>>>(qt, kt, vl, temp, maxk2, opart, lpart);
    gemm_proj<<<dim3(128, 3), 256, 0, stream>>>(wproj_b, opart, lpart, out, x);
}